// Round 1
// baseline (546.750 us; speedup 1.0000x reference)
//
#include <hip/hip_runtime.h>

// ScalingAndSquaring: v <- v + warp(v), 7 steps, (2,3,160,160,160) f32.
// out(d,h,w) = v(d,h,w) + trilinear v(z~w, y~h, x~d)  (self-transposed gather).
// Strategy: per-block 32(d) x 32(w) tile at fixed h-plane, staged via LDS so
// global reads/writes are w-coalesced while gathers run with d-fast lanes
// (x is the innermost storage axis -> lane-contiguous gather addresses).

constexpr int SZ  = 160;
constexpr int HW  = SZ * SZ;          // 25600
constexpr int DHW = SZ * SZ * SZ;     // 4096000

__global__ __launch_bounds__(256, 4)
void warp_step_kernel(const float* __restrict__ src,
                      float* __restrict__ dst,
                      float inScale)
{
    // --- XCD-contiguous swizzle: 8000 blocks, 8 XCDs, 1000 contiguous each ---
    const int wg = (int)blockIdx.x;                 // 0..7999
    const int r  = (wg & 7) * 1000 + (wg >> 3);     // bijective (8000 % 8 == 0)
    const int h0  = r % SZ;                         // H-axis plane
    const int t   = r / SZ;                         // 0..49
    const int bat = t / 25;                         // batch
    const int tt  = t % 25;
    const int a0  = (tt % 5) * 32;                  // D-axis tile base
    const int c0  = (tt / 5) * 32;                  // W-axis tile base

    const float* __restrict__ vb = src + (size_t)bat * 3 * DHW;
    float*       __restrict__ db = dst + (size_t)bat * 3 * DHW;

    // tile[ch][w_local][d_local], stride 33 -> conflict-free in both phases
    __shared__ float tile[3][32][33];

    const int tid  = (int)threadIdx.x;
    const int lc   = tid & 31;    // phase 1/3: w offset (coalesced global axis)
    const int prow = tid >> 5;    // 0..7

    // --- phase 1: stage own-voxel v tile (scaled), coalesced reads ---
    #pragma unroll
    for (int p = 0; p < 12; ++p) {
        const int row = prow + (p << 3);            // 0..95 = ch*32 + a
        const int ch  = row >> 5;
        const int a   = row & 31;
        tile[ch][lc][a] =
            vb[ch * DHW + (a0 + a) * HW + h0 * SZ + c0 + lc] * inScale;
    }
    __syncthreads();

    // --- phase 2: d-fast lanes; gathers are x-contiguous per wave ---
    const int a  = tid & 31;      // d_local  (lane-fast)
    const int cb = tid >> 5;      // 0..7     (w_local base)
    const float gx = (float)(a0 + a);   // d feeds grid_sample's x slot
    const float gy = (float)h0;         // h feeds y slot

    #pragma unroll 1
    for (int i = 0; i < 4; ++i) {
        const int c = cb + (i << 3);    // w_local
        const float gz = (float)(c0 + c);   // w feeds z slot
        const float v0 = tile[0][c][a];
        const float v1 = tile[1][c][a];
        const float v2 = tile[2][c][a];

        // reference op sequence (incl. divide) to keep rounding close
        float ix = ((2.0f * ((gx + v0) / 159.0f - 0.5f) + 1.0f) * 160.0f - 1.0f) * 0.5f;
        float iy = ((2.0f * ((gy + v1) / 159.0f - 0.5f) + 1.0f) * 160.0f - 1.0f) * 0.5f;
        float iz = ((2.0f * ((gz + v2) / 159.0f - 0.5f) + 1.0f) * 160.0f - 1.0f) * 0.5f;
        ix = fminf(fmaxf(ix, 0.0f), 159.0f);
        iy = fminf(fmaxf(iy, 0.0f), 159.0f);
        iz = fminf(fmaxf(iz, 0.0f), 159.0f);

        const float fx = floorf(ix), fy = floorf(iy), fz = floorf(iz);
        const float wx = ix - fx,  wy = iy - fy,  wz = iz - fz;
        const int x0 = (int)fx, y0 = (int)fy, z0 = (int)fz;
        const int x1 = min(x0 + 1, SZ - 1);
        const int y1 = min(y0 + 1, SZ - 1);
        const int z1 = min(z0 + 1, SZ - 1);

        const int r00 = (z0 * SZ + y0) * SZ;
        const int r01 = (z0 * SZ + y1) * SZ;
        const int r10 = (z1 * SZ + y0) * SZ;
        const int r11 = (z1 * SZ + y1) * SZ;

        const float wy0 = 1.0f - wy, wz0 = 1.0f - wz;
        const float w00 = wz0 * wy0, w01 = wz0 * wy;
        const float w10 = wz  * wy0, w11 = wz  * wy;

        const float own0 = v0, own1 = v1, own2 = v2;
        float res[3];
        #pragma unroll
        for (int ch = 0; ch < 3; ++ch) {
            const float* __restrict__ pc = vb + ch * DHW;
            const float l00 = pc[r00 + x0], h00 = pc[r00 + x1];
            const float l01 = pc[r01 + x0], h01 = pc[r01 + x1];
            const float l10 = pc[r10 + x0], h10 = pc[r10 + x1];
            const float l11 = pc[r11 + x0], h11 = pc[r11 + x1];
            const float s00 = l00 + wx * (h00 - l00);
            const float s01 = l01 + wx * (h01 - l01);
            const float s10 = l10 + wx * (h10 - l10);
            const float s11 = l11 + wx * (h11 - l11);
            const float interp = (s00 * w00 + s01 * w01) + (s10 * w10 + s11 * w11);
            res[ch] = interp;
        }
        // in-place: only this thread ever touches (c, a) slots
        tile[0][c][a] = own0 + res[0] * inScale;
        tile[1][c][a] = own1 + res[1] * inScale;
        tile[2][c][a] = own2 + res[2] * inScale;
    }
    __syncthreads();

    // --- phase 3: coalesced writes ---
    #pragma unroll
    for (int p = 0; p < 12; ++p) {
        const int row = prow + (p << 3);
        const int ch  = row >> 5;
        const int a2  = row & 31;
        db[ch * DHW + (a0 + a2) * HW + h0 * SZ + c0 + lc] = tile[ch][lc][a2];
    }
}

extern "C" void kernel_launch(void* const* d_in, const int* in_sizes, int n_in,
                              void* d_out, int out_size, void* d_ws, size_t ws_size,
                              hipStream_t stream)
{
    const float* vin = (const float*)d_in[0];
    float* out = (float*)d_out;
    float* ws  = (float*)d_ws;   // needs >= 2*3*160^3*4 = 98,304,000 bytes

    dim3 grid(8000), block(256);
    // 7 steps, ping-pong so the final result lands in d_out.
    warp_step_kernel<<<grid, block, 0, stream>>>(vin, out, 1.0f / 128.0f); // v1
    warp_step_kernel<<<grid, block, 0, stream>>>(out, ws,  1.0f);          // v2
    warp_step_kernel<<<grid, block, 0, stream>>>(ws,  out, 1.0f);          // v3
    warp_step_kernel<<<grid, block, 0, stream>>>(out, ws,  1.0f);          // v4
    warp_step_kernel<<<grid, block, 0, stream>>>(ws,  out, 1.0f);          // v5
    warp_step_kernel<<<grid, block, 0, stream>>>(out, ws,  1.0f);          // v6
    warp_step_kernel<<<grid, block, 0, stream>>>(ws,  out, 1.0f);          // v7
}